// Round 6
// baseline (904.387 us; speedup 1.0000x reference)
//
#include <hip/hip_runtime.h>

using short8  = __attribute__((ext_vector_type(8))) short;
using f32x4   = __attribute__((ext_vector_type(4))) float;

namespace {
constexpr int T_  = 16;
constexpr int F_  = 256;
constexpr int QLD = 772;   // sQKV stride (floats): 772 % 32 == 4

__device__ __forceinline__ unsigned short f32_to_bf16_rn(float v) {
  unsigned u = __builtin_bit_cast(unsigned, v);
  unsigned r = u + 0x7FFFu + ((u >> 16) & 1u);
  return (unsigned short)(r >> 16);
}
// v ~= hi + lo with |err| ~ 2^-17 |v|
__device__ __forceinline__ void split_hi_lo(float v, unsigned short& h, unsigned short& l) {
  unsigned u = __builtin_bit_cast(unsigned, v);
  unsigned r = (u + 0x7FFFu + ((u >> 16) & 1u)) & 0xFFFF0000u;
  h = (unsigned short)(r >> 16);
  float lo = v - __builtin_bit_cast(float, r);
  l = f32_to_bf16_rn(lo);
}
} // namespace

// ---- prep: gather weights into MFMA B-fragment-linear bf16 chunks ----
// chunk (tile,s): 64 lanes x 8 bf16 = 1KB, lane l holds B[k = s*32+(l>>4)*8 + j][n = tile*16 + (l&15)]
// tiles 0..47: B = [Wq|Wk|Wv]; tiles 48..63: B[k=f][n=e] = lin_w[e][f]
extern "C" __global__ void __launch_bounds__(256)
build_frags(const float* __restrict__ Wq, const float* __restrict__ Wk,
            const float* __restrict__ Wv, const float* __restrict__ linw,
            unsigned short* __restrict__ frag) {
  const int g = blockIdx.x * 256 + threadIdx.x;   // 32768 threads total
  const int l = g & 63;
  const int chunk = g >> 6;                       // 0..511
  const int s = chunk & 7;
  const int tile = chunk >> 3;                    // 0..63
  const int lr = l & 15, lg = l >> 4;
  const int kbase = s * 32 + lg * 8;
  unsigned short v[8];
  if (tile < 48) {
    const int n = tile * 16 + lr;                 // 0..767
    const float* src = (n < 256) ? (Wq + n) : ((n < 512) ? (Wk + (n - 256)) : (Wv + (n - 512)));
#pragma unroll
    for (int j = 0; j < 8; ++j) v[j] = f32_to_bf16_rn(src[(kbase + j) * F_]);
  } else {
    const int e = (tile - 48) * 16 + lr;
    const float* src = linw + e * F_ + kbase;
#pragma unroll
    for (int j = 0; j < 8; ++j) v[j] = f32_to_bf16_rn(src[j]);
  }
  short8 pack;
#pragma unroll
  for (int j = 0; j < 8; ++j) pack[j] = (short)v[j];
  *(short8*)(frag + chunk * 512 + l * 8) = pack;
}

extern "C" __global__ void __launch_bounds__(256, 3)
fused_temporal_attn(const float* __restrict__ x, const float* __restrict__ pos_emb,
                    const unsigned short* __restrict__ frag,
                    const float* __restrict__ lin_b, float* __restrict__ out) {
  // Single LDS buffer: [ q(0:256) | k(256:512) | v(512:768) ].
  // q-region doubles as (a) temporal staging in A-fragment-linear layout (phase 0-2a),
  // (b) Q output (phase 2b-3), (c) att_out (phase 3-4).
  __shared__ float sQKV[T_][QLD];

  const int n = blockIdx.x;
  const int tid = threadIdx.x;
  const int wv = tid >> 6;   // wave 0..3
  const int l  = tid & 63;
  const int lr = l & 15;     // MFMA: A-row / B-col / C-col
  const int lg = l >> 4;     // MFMA: k-group / C row-group

  const float* __restrict__ xb = x + (size_t)n * (T_ * F_);

  // ---------------- Phase 0: temporal = x + pos_emb, staged in fragment-linear layout ----------------
  // slot (sh, lane): temporal[row = lane&15][k0..k0+3], k0 = (sh>>1)*32 + (lane>>4)*8 + (sh&1)*4,
  // stored at &sQKV[sh][lane*4]  -> conflict-free LDS (consecutive lanes, consecutive 16B)
  {
#pragma unroll
    for (int it = 0; it < 4; ++it) {
      const int sh = it * 4 + wv;
      const int k0 = (sh >> 1) * 32 + lg * 8 + (sh & 1) * 4;
      float4 a = *(const float4*)(xb + lr * 256 + k0);
      const float4 b = *(const float4*)(pos_emb + lr * 256 + k0);
      a.x += b.x; a.y += b.y; a.z += b.z; a.w += b.w;
      *(float4*)&sQKV[sh][l * 4] = a;
    }
  }
  __syncthreads();

  // ---------------- Phase 2a: A-fragments -> registers (hi/lo bf16 split) ----------------
  short8 ah[8], al[8];
#pragma unroll
  for (int s = 0; s < 8; ++s) {
    const float4 a0 = *(const float4*)&sQKV[2 * s][l * 4];       // k = s*32+lg*8 + 0..3
    const float4 a1 = *(const float4*)&sQKV[2 * s + 1][l * 4];   // k = s*32+lg*8 + 4..7
    const float av[8] = {a0.x, a0.y, a0.z, a0.w, a1.x, a1.y, a1.z, a1.w};
#pragma unroll
    for (int j = 0; j < 8; ++j) {
      unsigned short hh, ll;
      split_hi_lo(av[j], hh, ll);
      ah[s][j] = (short)hh; al[s][j] = (short)ll;
    }
  }
  __syncthreads();   // all staging reads done before q-region is overwritten

  // ---------------- Phase 2b: QKV = temporal @ [Wq|Wk|Wv] via MFMA ----------------
  // wave wv owns N-tiles wv*12 .. wv*12+11 (16 cols each) of the 768-wide output
  {
    f32x4 acc[12];
#pragma unroll
    for (int t = 0; t < 12; ++t) acc[t] = (f32x4){0.f, 0.f, 0.f, 0.f};

#pragma unroll
    for (int s = 0; s < 8; ++s) {
      const unsigned short* bp = frag + (size_t)((wv * 12) * 8 + s) * 512 + l * 8;
#pragma unroll
      for (int t = 0; t < 12; ++t) {
        const short8 b = *(const short8*)(bp + t * 4096);   // tile stride = 8 chunks * 512
        acc[t] = __builtin_amdgcn_mfma_f32_16x16x32_bf16(ah[s], b, acc[t], 0, 0, 0);
        acc[t] = __builtin_amdgcn_mfma_f32_16x16x32_bf16(al[s], b, acc[t], 0, 0, 0);
      }
    }
    // C layout: col = lr, row = lg*4 + reg
#pragma unroll
    for (int t = 0; t < 12; ++t) {
      const int col = (wv * 12 + t) * 16 + lr;
#pragma unroll
      for (int r = 0; r < 4; ++r) sQKV[lg * 4 + r][col] = acc[t][r];
    }
  }
  __syncthreads();

  // ---------------- Phase 3: attention (thread = (head, query-row)) — fp32 ----------------
  {
    const int h = tid >> 4;   // 0..15
    const int i = tid & 15;   // 0..15
    constexpr float SMV[16] = {0.f, 1.f, 3.f, 4.f, 7.f, 9.f, 12.f, 14.f,
                               17.f, 19.f, 23.f, 26.f, 28.f, 31.f, 35.f, 38.f};
    const float smi = SMV[i];

    float qv[16];
#pragma unroll
    for (int dd = 0; dd < 4; ++dd) {
      const float4 q4 = *(const float4*)&sQKV[i][h * 16 + dd * 4];
      qv[4 * dd + 0] = q4.x; qv[4 * dd + 1] = q4.y; qv[4 * dd + 2] = q4.z; qv[4 * dd + 3] = q4.w;
    }

    float p[16];
    float mx = -3.0e38f;
#pragma unroll
    for (int j = 0; j < 16; ++j) {
      float dot = 0.f;
#pragma unroll
      for (int dd = 0; dd < 4; ++dd) {
        const float4 k4 = *(const float4*)&sQKV[j][F_ + h * 16 + dd * 4];
        dot = fmaf(qv[4 * dd + 0], k4.x, dot);
        dot = fmaf(qv[4 * dd + 1], k4.y, dot);
        dot = fmaf(qv[4 * dd + 2], k4.z, dot);
        dot = fmaf(qv[4 * dd + 3], k4.w, dot);
      }
      const float diff = (j < i) ? (smi - SMV[j]) : 1.0f;
      float sc = (dot * 0.25f) / diff;
      sc = (j <= i) ? sc : -3.0e38f;
      p[j] = sc;
      mx = fmaxf(mx, sc);
    }
    float den = 0.f;
#pragma unroll
    for (int j = 0; j < 16; ++j) {
      float e = __expf(p[j] - mx);
      e = (j <= i) ? e : 0.f;
      p[j] = e;
      den += e;
    }
    const float inv = 1.0f / den;

    float o[16];
#pragma unroll
    for (int d = 0; d < 16; ++d) o[d] = 0.f;
#pragma unroll
    for (int j = 0; j < 16; ++j) {
      const float pj = p[j] * inv;
#pragma unroll
      for (int dd = 0; dd < 4; ++dd) {
        const float4 v4 = *(const float4*)&sQKV[j][2 * F_ + h * 16 + dd * 4];
        o[4 * dd + 0] = fmaf(pj, v4.x, o[4 * dd + 0]);
        o[4 * dd + 1] = fmaf(pj, v4.y, o[4 * dd + 1]);
        o[4 * dd + 2] = fmaf(pj, v4.z, o[4 * dd + 2]);
        o[4 * dd + 3] = fmaf(pj, v4.w, o[4 * dd + 3]);
      }
    }
    __syncthreads();   // all q/k/v reads done before overwriting q region with att_out
#pragma unroll
    for (int dd = 0; dd < 4; ++dd)
      *(float4*)&sQKV[i][h * 16 + dd * 4] =
          make_float4(o[4 * dd + 0], o[4 * dd + 1], o[4 * dd + 2], o[4 * dd + 3]);
  }
  __syncthreads();

  // ---------------- Phase 4: FF via MFMA + epilogue ----------------
  // wave wv owns N-tiles wv*4 .. wv*4+3 of the 256-wide FF output (frag tiles 48+)
  {
    f32x4 fa[4];
#pragma unroll
    for (int t = 0; t < 4; ++t) fa[t] = (f32x4){0.f, 0.f, 0.f, 0.f};

#pragma unroll 2
    for (int s = 0; s < 8; ++s) {
      const float* ap = &sQKV[lr][s * 32 + lg * 8];   // att_out (q region, row-major)
      const float4 a0 = *(const float4*)ap;
      const float4 a1 = *(const float4*)(ap + 4);
      const float av[8] = {a0.x, a0.y, a0.z, a0.w, a1.x, a1.y, a1.z, a1.w};
      short8 fh, fl;
#pragma unroll
      for (int j = 0; j < 8; ++j) {
        unsigned short hh, ll;
        split_hi_lo(av[j], hh, ll);
        fh[j] = (short)hh; fl[j] = (short)ll;
      }
      const unsigned short* bp = frag + (size_t)((48 + wv * 4) * 8 + s) * 512 + l * 8;
#pragma unroll
      for (int t = 0; t < 4; ++t) {
        const short8 b = *(const short8*)(bp + t * 4096);
        fa[t] = __builtin_amdgcn_mfma_f32_16x16x32_bf16(fh, b, fa[t], 0, 0, 0);
        fa[t] = __builtin_amdgcn_mfma_f32_16x16x32_bf16(fl, b, fa[t], 0, 0, 0);
      }
    }

    float* outp = out + (size_t)n * (T_ * F_);
#pragma unroll
    for (int t = 0; t < 4; ++t) {
      const int col = (wv * 4 + t) * 16 + lr;
      const float bias = lin_b[col];
#pragma unroll
      for (int r = 0; r < 4; ++r) {
        const int row = lg * 4 + r;
        // residual: att (LDS q-region) + temporal recomputed exactly from global
        const float temporal = xb[row * 256 + col] + pos_emb[row * 256 + col];
        const float val = fmaxf(fa[t][r] + bias, 0.f) + sQKV[row][col] + temporal;
        outp[row * F_ + col] = val;
      }
    }
  }
}

extern "C" void kernel_launch(void* const* d_in, const int* in_sizes, int n_in,
                              void* d_out, int out_size, void* d_ws, size_t ws_size,
                              hipStream_t stream) {
  const float* x   = (const float*)d_in[0];
  const float* pos = (const float*)d_in[1];
  const float* Wq  = (const float*)d_in[2];
  const float* Wk  = (const float*)d_in[3];
  const float* Wv  = (const float*)d_in[4];
  const float* lw  = (const float*)d_in[5];
  const float* lb  = (const float*)d_in[6];
  float* out = (float*)d_out;
  unsigned short* frag = (unsigned short*)d_ws;   // 64 tiles * 8 ksteps * 1KB = 512 KB

  build_frags<<<128, 256, 0, stream>>>(Wq, Wk, Wv, lw, frag);
  fused_temporal_attn<<<16384, 256, 0, stream>>>(x, pos, frag, lb, out);
}